// Round 7
// baseline (841.001 us; speedup 1.0000x reference)
//
#include <hip/hip_runtime.h>
#include <math.h>

#define NH 32
#define HD 128
#define BS 16
#define MAXB 64
#define HID 4096
#define NBATCH 16
#define QKV_R 12288
#define SCALE 0.08838834764831845f  // 1/sqrt(128)
#define TPC 128                     // tokens per chunk
#define NCHUNK 8                    // max chunks (MAXB*BS / TPC)

typedef float floatv4 __attribute__((ext_vector_type(4)));

// PROBE A (baseline): v3 body + runtime rep loop so the dispatch outranks the
// harness fill kernels in rocprof and exposes FETCH/VALUBusy for the gemv.
__global__ __launch_bounds__(256, 4) void gemv16_v3_rep(
    const float* __restrict__ x, const float* __restrict__ W,
    float* __restrict__ y, int R, int reps) {
  const int r0 = blockIdx.x * 4;
  const int tid = threadIdx.x;
  const int wave = tid >> 6, lane = tid & 63;
  const int b0 = wave * 4;

  for (int rep = 0; rep < reps; ++rep) {
    asm volatile("" ::: "memory");  // no cross-rep CSE of loads
    float acc[4][4];
#pragma unroll
    for (int r = 0; r < 4; ++r)
#pragma unroll
      for (int bb = 0; bb < 4; ++bb) acc[r][bb] = 0.f;

#pragma unroll 2
    for (int it = 0; it < 16; ++it) {
      const int j = it * 256 + lane * 4;
      float4 wv[4];
#pragma unroll
      for (int r = 0; r < 4; ++r)
        wv[r] = *reinterpret_cast<const float4*>(&W[(size_t)(r0 + r) * 4096 + j]);
      float4 xv[4];
#pragma unroll
      for (int bb = 0; bb < 4; ++bb)
        xv[bb] = *reinterpret_cast<const float4*>(&x[(size_t)(b0 + bb) * 4096 + j]);
#pragma unroll
      for (int r = 0; r < 4; ++r)
#pragma unroll
        for (int bb = 0; bb < 4; ++bb)
          acc[r][bb] += wv[r].x * xv[bb].x + wv[r].y * xv[bb].y +
                        wv[r].z * xv[bb].z + wv[r].w * xv[bb].w;
    }

#pragma unroll
    for (int r = 0; r < 4; ++r)
#pragma unroll
      for (int bb = 0; bb < 4; ++bb) {
        float v = acc[r][bb];
#pragma unroll
        for (int off = 32; off; off >>= 1) v += __shfl_xor(v, off, 64);
        if (lane == 0) y[(size_t)(b0 + bb) * R + r0 + r] = v;
      }
  }
}

// PROBE B (treatment): W loaded via nontemporal ext-vector loads so the W
// stream doesn't evict x from L2/L3 (x-eviction hypothesis test).
__global__ __launch_bounds__(256, 4) void gemv16_v4nt_rep(
    const float* __restrict__ x, const float* __restrict__ W,
    float* __restrict__ y, int R, int reps) {
  const int r0 = blockIdx.x * 4;
  const int tid = threadIdx.x;
  const int wave = tid >> 6, lane = tid & 63;
  const int b0 = wave * 4;

  for (int rep = 0; rep < reps; ++rep) {
    asm volatile("" ::: "memory");
    float acc[4][4];
#pragma unroll
    for (int r = 0; r < 4; ++r)
#pragma unroll
      for (int bb = 0; bb < 4; ++bb) acc[r][bb] = 0.f;

#pragma unroll 2
    for (int it = 0; it < 16; ++it) {
      const int j = it * 256 + lane * 4;
      floatv4 wv[4];
#pragma unroll
      for (int r = 0; r < 4; ++r)
        wv[r] = __builtin_nontemporal_load(
            reinterpret_cast<const floatv4*>(&W[(size_t)(r0 + r) * 4096 + j]));
      float4 xv[4];
#pragma unroll
      for (int bb = 0; bb < 4; ++bb)
        xv[bb] = *reinterpret_cast<const float4*>(&x[(size_t)(b0 + bb) * 4096 + j]);
#pragma unroll
      for (int r = 0; r < 4; ++r)
#pragma unroll
        for (int bb = 0; bb < 4; ++bb)
          acc[r][bb] += wv[r][0] * xv[bb].x + wv[r][1] * xv[bb].y +
                        wv[r][2] * xv[bb].z + wv[r][3] * xv[bb].w;
    }

#pragma unroll
    for (int r = 0; r < 4; ++r)
#pragma unroll
      for (int bb = 0; bb < 4; ++bb) {
        float v = acc[r][bb];
#pragma unroll
        for (int off = 32; off; off >>= 1) v += __shfl_xor(v, off, 64);
        if (lane == 0) y[(size_t)(b0 + bb) * R + r0 + r] = v;
      }
  }
}

// Flash-decoding chunk kernel (unchanged, ~50us, characterized).
__global__ __launch_bounds__(256) void attn_split(
    const float* __restrict__ qkv, const float* __restrict__ cs_cache,
    const float* __restrict__ kcache, const float* __restrict__ vcache,
    const int* __restrict__ pos_ids, const int* __restrict__ btab,
    const int* __restrict__ ctx_len, float* __restrict__ o_part,
    float* __restrict__ m_part, float* __restrict__ l_part) {
  const int bh = blockIdx.x;
  const int b = bh >> 5, h = bh & 31;
  const int c = blockIdx.y;
  const int ctx = ctx_len[b];
  const int t0 = c * TPC;
  if (t0 >= ctx) return;
  const int tend = min(t0 + TPC, ctx);
  const int n = tend - t0;
  const int last = ctx - 1;

  const int tid = threadIdx.x;
  const int wave = tid >> 6, lane = tid & 63;
  const int grp = lane >> 3, sub = lane & 7;
  const int gid = wave * 8 + grp;

  __shared__ float q_rot[HD], k_rot[HD], v_new[HD];
  __shared__ float scores[TPC];
  __shared__ int blk_base[TPC / BS];
  __shared__ float redm[4], reds[4];
  __shared__ float ow[4][HD];

  const int pos = pos_ids[b];
  const float* qp = qkv + (size_t)b * QKV_R + h * HD;
  const float* kp = qp + 4096;
  const float* vp = qp + 8192;
  const float* cs = cs_cache + (size_t)pos * HD;

  if (tid < 64) {
    const float co = cs[tid], si = cs[64 + tid];
    const float a1 = qp[tid], a2 = qp[tid + 64];
    q_rot[tid] = a1 * co - a2 * si;
    q_rot[tid + 64] = a2 * co + a1 * si;
    const float b1 = kp[tid], b2 = kp[tid + 64];
    k_rot[tid] = b1 * co - b2 * si;
    k_rot[tid + 64] = b2 * co + b1 * si;
  } else if (tid < 192) {
    v_new[tid - 64] = vp[tid - 64];
  } else if (tid < 192 + TPC / BS) {
    const int i = tid - 192;
    const int bt_idx = (t0 >> 4) + i;
    blk_base[i] = (bt_idx < MAXB) ? btab[b * MAXB + bt_idx] : 0;
  }
  __syncthreads();

  float4 qf[4];
#pragma unroll
  for (int i = 0; i < 4; ++i)
    qf[i] = *reinterpret_cast<const float4*>(&q_rot[sub * 4 + i * 32]);

  for (int t = t0 + gid; t < tend; t += 32) {
    float4 kv[4];
    if (t == last) {
#pragma unroll
      for (int i = 0; i < 4; ++i)
        kv[i] = *reinterpret_cast<const float4*>(&k_rot[sub * 4 + i * 32]);
    } else {
      const int blk = blk_base[(t - t0) >> 4];
      const float* kr = kcache + ((((size_t)blk << 4) + (t & 15)) * NH + h) * HD;
#pragma unroll
      for (int i = 0; i < 4; ++i)
        kv[i] = *reinterpret_cast<const float4*>(&kr[sub * 4 + i * 32]);
    }
    float d0 = kv[0].x * qf[0].x + kv[0].y * qf[0].y + kv[0].z * qf[0].z + kv[0].w * qf[0].w;
    float d1 = kv[1].x * qf[1].x + kv[1].y * qf[1].y + kv[1].z * qf[1].z + kv[1].w * qf[1].w;
    float d2 = kv[2].x * qf[2].x + kv[2].y * qf[2].y + kv[2].z * qf[2].z + kv[2].w * qf[2].w;
    float d3 = kv[3].x * qf[3].x + kv[3].y * qf[3].y + kv[3].z * qf[3].z + kv[3].w * qf[3].w;
    float d = (d0 + d1) + (d2 + d3);
    d += __shfl_xor(d, 1, 64);
    d += __shfl_xor(d, 2, 64);
    d += __shfl_xor(d, 4, 64);
    if (sub == 0) scores[t - t0] = d * SCALE;
  }
  __syncthreads();

  float m = (tid < n) ? scores[tid] : -1e30f;
#pragma unroll
  for (int off = 32; off; off >>= 1) m = fmaxf(m, __shfl_xor(m, off, 64));
  if (lane == 0) redm[wave] = m;
  __syncthreads();
  m = fmaxf(fmaxf(redm[0], redm[1]), fmaxf(redm[2], redm[3]));

  float ssum = 0.f;
  if (tid < n) {
    const float e = expf(scores[tid] - m);
    scores[tid] = e;
    ssum = e;
  }
#pragma unroll
  for (int off = 32; off; off >>= 1) ssum += __shfl_xor(ssum, off, 64);
  if (lane == 0) reds[wave] = ssum;
  __syncthreads();
  const float l = reds[0] + reds[1] + reds[2] + reds[3];

  float4 oacc[4];
#pragma unroll
  for (int i = 0; i < 4; ++i) oacc[i] = make_float4(0.f, 0.f, 0.f, 0.f);

  for (int t = t0 + gid; t < tend; t += 32) {
    const float p = scores[t - t0];
    float4 vv[4];
    if (t == last) {
#pragma unroll
      for (int i = 0; i < 4; ++i)
        vv[i] = *reinterpret_cast<const float4*>(&v_new[sub * 4 + i * 32]);
    } else {
      const int blk = blk_base[(t - t0) >> 4];
      const float* vr = vcache + ((((size_t)blk << 4) + (t & 15)) * NH + h) * HD;
#pragma unroll
      for (int i = 0; i < 4; ++i)
        vv[i] = *reinterpret_cast<const float4*>(&vr[sub * 4 + i * 32]);
    }
#pragma unroll
    for (int i = 0; i < 4; ++i) {
      oacc[i].x += p * vv[i].x;
      oacc[i].y += p * vv[i].y;
      oacc[i].z += p * vv[i].z;
      oacc[i].w += p * vv[i].w;
    }
  }

#pragma unroll
  for (int i = 0; i < 4; ++i) {
#pragma unroll
    for (int off = 8; off <= 32; off <<= 1) {
      oacc[i].x += __shfl_xor(oacc[i].x, off, 64);
      oacc[i].y += __shfl_xor(oacc[i].y, off, 64);
      oacc[i].z += __shfl_xor(oacc[i].z, off, 64);
      oacc[i].w += __shfl_xor(oacc[i].w, off, 64);
    }
  }
  if (grp == 0) {
#pragma unroll
    for (int i = 0; i < 4; ++i)
      *reinterpret_cast<float4*>(&ow[wave][sub * 4 + i * 32]) = oacc[i];
  }
  __syncthreads();
  if (tid < HD) {
    const float o = ow[0][tid] + ow[1][tid] + ow[2][tid] + ow[3][tid];
    o_part[((size_t)bh * NCHUNK + c) * HD + tid] = o;
    if (tid == 0) {
      m_part[bh * NCHUNK + c] = m;
      l_part[bh * NCHUNK + c] = l;
    }
  }
}

__global__ __launch_bounds__(128) void attn_combine(
    const float* __restrict__ o_part, const float* __restrict__ m_part,
    const float* __restrict__ l_part, const int* __restrict__ ctx_len,
    float* __restrict__ attn_out) {
  const int bh = blockIdx.x;
  const int b = bh >> 5, h = bh & 31;
  const int ctx = ctx_len[b];
  const int nc = (ctx + TPC - 1) / TPC;
  const int d = threadIdx.x;

  float M = -1e30f;
  for (int c = 0; c < nc; ++c) M = fmaxf(M, m_part[bh * NCHUNK + c]);
  float L = 0.f, o = 0.f;
  for (int c = 0; c < nc; ++c) {
    const float sc = expf(m_part[bh * NCHUNK + c] - M);
    L += l_part[bh * NCHUNK + c] * sc;
    o += o_part[((size_t)bh * NCHUNK + c) * HD + d] * sc;
  }
  attn_out[(size_t)b * HID + h * HD + d] = o / L;
}

extern "C" void kernel_launch(void* const* d_in, const int* in_sizes, int n_in,
                              void* d_out, int out_size, void* d_ws, size_t ws_size,
                              hipStream_t stream) {
  const float* hidden = (const float*)d_in[0];
  const float* qkv_w  = (const float*)d_in[1];
  const float* out_w  = (const float*)d_in[2];
  const float* cs     = (const float*)d_in[3];
  const float* kc     = (const float*)d_in[4];
  const float* vc     = (const float*)d_in[5];
  const int* pos      = (const int*)d_in[6];
  const int* bt       = (const int*)d_in[7];
  const int* cl       = (const int*)d_in[9];
  float* out = (float*)d_out;

  float* ws_qkv  = (float*)d_ws;
  float* ws_attn = ws_qkv + NBATCH * QKV_R;
  float* ws_op   = ws_attn + NBATCH * HID;
  float* ws_m    = ws_op + (size_t)NBATCH * NH * NCHUNK * HD;
  float* ws_l    = ws_m + NBATCH * NH * NCHUNK;

  // PROBE A: baseline gemv, 3 internal reps (~220us dispatch -> top-5 w/ counters)
  gemv16_v3_rep<<<QKV_R / 4, 256, 0, stream>>>(hidden, qkv_w, ws_qkv, QKV_R, 3);
  attn_split<<<dim3(NBATCH * NH, NCHUNK), 256, 0, stream>>>(
      ws_qkv, cs, kc, vc, pos, bt, cl, ws_op, ws_m, ws_l);
  attn_combine<<<NBATCH * NH, 128, 0, stream>>>(ws_op, ws_m, ws_l, cl, ws_attn);
  // PROBE B: nt-W gemv, 16 internal reps (~200-400us dispatch -> top-5 w/ counters)
  gemv16_v4nt_rep<<<HID / 4, 256, 0, stream>>>(ws_attn, out_w, out, HID, 16);
}

// Round 8
// 353.621 us; speedup vs baseline: 2.3783x; 2.3783x over previous
//
#include <hip/hip_runtime.h>
#include <math.h>

#define NH 32
#define HD 128
#define BS 16
#define MAXB 64
#define HID 4096
#define NBATCH 16
#define QKV_R 12288
#define SCALE 0.08838834764831845f  // 1/sqrt(128)
#define TPC 128                     // tokens per chunk (attn split)
#define NCHUNK 8                    // max chunks (MAXB*BS / TPC)
#define KSPLIT 4
#define KC 1024                     // 4096 / KSPLIT

// v6 "attn-shaped" gemv: grid (R/4, KSPLIT). Block = 4 waves; wave w owns
// batches 4w..4w+3. Each wave preloads its x K-slice into regs (16 float4,
// one L2 burst), then the hot loop streams PURE W (4 float4/iter, 2-stage
// double buffer) with FMAs from registers. Writes per-chunk partials:
// yp[(chunk*16 + b)*R + r].
__global__ __launch_bounds__(256, 4) void gemv16_v6(
    const float* __restrict__ x, const float* __restrict__ W,
    float* __restrict__ yp, int R) {
  const int r0 = blockIdx.x * 4;
  const int kc0 = blockIdx.y * KC;
  const int tid = threadIdx.x;
  const int wave = tid >> 6, lane = tid & 63;
  const int b0 = wave * 4;

  // x preload: xr[bb][it] covers K = kc0 + it*256 + lane*4 (+0..3)
  float4 xr[4][4];
#pragma unroll
  for (int bb = 0; bb < 4; ++bb)
#pragma unroll
    for (int it = 0; it < 4; ++it)
      xr[bb][it] = *reinterpret_cast<const float4*>(
          &x[(size_t)(b0 + bb) * 4096 + kc0 + it * 256 + lane * 4]);

  const float* wb = W + (size_t)r0 * 4096 + kc0 + lane * 4;
  float4 w0[4], w1[4];
#pragma unroll
  for (int r = 0; r < 4; ++r)
    w0[r] = *reinterpret_cast<const float4*>(wb + (size_t)r * 4096);

  float acc[4][4];
#pragma unroll
  for (int r = 0; r < 4; ++r)
#pragma unroll
    for (int bb = 0; bb < 4; ++bb) acc[r][bb] = 0.f;

#pragma unroll
  for (int it = 0; it < 4; ++it) {
    if (it < 3) {
#pragma unroll
      for (int r = 0; r < 4; ++r)
        w1[r] = *reinterpret_cast<const float4*>(
            wb + (size_t)r * 4096 + (it + 1) * 256);
    }
#pragma unroll
    for (int r = 0; r < 4; ++r)
#pragma unroll
      for (int bb = 0; bb < 4; ++bb)
        acc[r][bb] += w0[r].x * xr[bb][it].x + w0[r].y * xr[bb][it].y +
                      w0[r].z * xr[bb][it].z + w0[r].w * xr[bb][it].w;
#pragma unroll
    for (int r = 0; r < 4; ++r) w0[r] = w1[r];
  }

#pragma unroll
  for (int r = 0; r < 4; ++r)
#pragma unroll
    for (int bb = 0; bb < 4; ++bb) {
      float v = acc[r][bb];
#pragma unroll
      for (int off = 32; off; off >>= 1) v += __shfl_xor(v, off, 64);
      if (lane == 0)
        yp[((size_t)blockIdx.y * 16 + b0 + bb) * R + r0 + r] = v;
    }
}

// Sum KSPLIT partial slices into y (used for the output projection).
__global__ __launch_bounds__(256) void combine_k(
    const float* __restrict__ p, float* __restrict__ y, int R) {
  const int i = blockIdx.x * 256 + threadIdx.x;
  if (i < 16 * R) {
    float v = 0.f;
#pragma unroll
    for (int c = 0; c < KSPLIT; ++c) v += p[(size_t)c * 16 * R + i];
    y[i] = v;
  }
}

// Flash-decoding chunk kernel. Reads qkv as KSPLIT partial slices and sums
// them while building q/k/v (folded combine). New k/v substituted at
// s == ctx-1 (block_tables is a permutation => disjoint rows).
__global__ __launch_bounds__(256) void attn_split(
    const float* __restrict__ qkv_p, const float* __restrict__ cs_cache,
    const float* __restrict__ kcache, const float* __restrict__ vcache,
    const int* __restrict__ pos_ids, const int* __restrict__ btab,
    const int* __restrict__ ctx_len, float* __restrict__ o_part,
    float* __restrict__ m_part, float* __restrict__ l_part) {
  const int bh = blockIdx.x;
  const int b = bh >> 5, h = bh & 31;
  const int c = blockIdx.y;
  const int ctx = ctx_len[b];
  const int t0 = c * TPC;
  if (t0 >= ctx) return;
  const int tend = min(t0 + TPC, ctx);
  const int n = tend - t0;
  const int last = ctx - 1;

  const int tid = threadIdx.x;
  const int wave = tid >> 6, lane = tid & 63;
  const int grp = lane >> 3, sub = lane & 7;
  const int gid = wave * 8 + grp;

  __shared__ float q_rot[HD], k_rot[HD], v_new[HD];
  __shared__ float scores[TPC];
  __shared__ int blk_base[TPC / BS];
  __shared__ float redm[4], reds[4];
  __shared__ float ow[4][HD];

  const int pos = pos_ids[b];
  const size_t CS = (size_t)16 * QKV_R;  // chunk stride in partial buffer
  const float* qp = qkv_p + (size_t)b * QKV_R + h * HD;
  const float* cs = cs_cache + (size_t)pos * HD;

  if (tid < 64) {
    const float co = cs[tid], si = cs[64 + tid];
    const float a1 = qp[tid] + qp[CS + tid] + qp[2 * CS + tid] + qp[3 * CS + tid];
    const float a2 = qp[tid + 64] + qp[CS + tid + 64] + qp[2 * CS + tid + 64] +
                     qp[3 * CS + tid + 64];
    q_rot[tid] = a1 * co - a2 * si;
    q_rot[tid + 64] = a2 * co + a1 * si;
    const float* kp = qp + 4096;
    const float b1 = kp[tid] + kp[CS + tid] + kp[2 * CS + tid] + kp[3 * CS + tid];
    const float b2 = kp[tid + 64] + kp[CS + tid + 64] + kp[2 * CS + tid + 64] +
                     kp[3 * CS + tid + 64];
    k_rot[tid] = b1 * co - b2 * si;
    k_rot[tid + 64] = b2 * co + b1 * si;
  } else if (tid < 192) {
    const int d = tid - 64;
    const float* vp = qp + 8192;
    v_new[d] = vp[d] + vp[CS + d] + vp[2 * CS + d] + vp[3 * CS + d];
  } else if (tid < 192 + TPC / BS) {
    const int i = tid - 192;
    const int bt_idx = (t0 >> 4) + i;
    blk_base[i] = (bt_idx < MAXB) ? btab[b * MAXB + bt_idx] : 0;
  }
  __syncthreads();

  float4 qf[4];
#pragma unroll
  for (int i = 0; i < 4; ++i)
    qf[i] = *reinterpret_cast<const float4*>(&q_rot[sub * 4 + i * 32]);

  for (int t = t0 + gid; t < tend; t += 32) {
    float4 kv[4];
    if (t == last) {
#pragma unroll
      for (int i = 0; i < 4; ++i)
        kv[i] = *reinterpret_cast<const float4*>(&k_rot[sub * 4 + i * 32]);
    } else {
      const int blk = blk_base[(t - t0) >> 4];
      const float* kr = kcache + ((((size_t)blk << 4) + (t & 15)) * NH + h) * HD;
#pragma unroll
      for (int i = 0; i < 4; ++i)
        kv[i] = *reinterpret_cast<const float4*>(&kr[sub * 4 + i * 32]);
    }
    float d0 = kv[0].x * qf[0].x + kv[0].y * qf[0].y + kv[0].z * qf[0].z + kv[0].w * qf[0].w;
    float d1 = kv[1].x * qf[1].x + kv[1].y * qf[1].y + kv[1].z * qf[1].z + kv[1].w * qf[1].w;
    float d2 = kv[2].x * qf[2].x + kv[2].y * qf[2].y + kv[2].z * qf[2].z + kv[2].w * qf[2].w;
    float d3 = kv[3].x * qf[3].x + kv[3].y * qf[3].y + kv[3].z * qf[3].z + kv[3].w * qf[3].w;
    float d = (d0 + d1) + (d2 + d3);
    d += __shfl_xor(d, 1, 64);
    d += __shfl_xor(d, 2, 64);
    d += __shfl_xor(d, 4, 64);
    if (sub == 0) scores[t - t0] = d * SCALE;
  }
  __syncthreads();

  float m = (tid < n) ? scores[tid] : -1e30f;
#pragma unroll
  for (int off = 32; off; off >>= 1) m = fmaxf(m, __shfl_xor(m, off, 64));
  if (lane == 0) redm[wave] = m;
  __syncthreads();
  m = fmaxf(fmaxf(redm[0], redm[1]), fmaxf(redm[2], redm[3]));

  float ssum = 0.f;
  if (tid < n) {
    const float e = expf(scores[tid] - m);
    scores[tid] = e;
    ssum = e;
  }
#pragma unroll
  for (int off = 32; off; off >>= 1) ssum += __shfl_xor(ssum, off, 64);
  if (lane == 0) reds[wave] = ssum;
  __syncthreads();
  const float l = reds[0] + reds[1] + reds[2] + reds[3];

  float4 oacc[4];
#pragma unroll
  for (int i = 0; i < 4; ++i) oacc[i] = make_float4(0.f, 0.f, 0.f, 0.f);

  for (int t = t0 + gid; t < tend; t += 32) {
    const float p = scores[t - t0];
    float4 vv[4];
    if (t == last) {
#pragma unroll
      for (int i = 0; i < 4; ++i)
        vv[i] = *reinterpret_cast<const float4*>(&v_new[sub * 4 + i * 32]);
    } else {
      const int blk = blk_base[(t - t0) >> 4];
      const float* vr = vcache + ((((size_t)blk << 4) + (t & 15)) * NH + h) * HD;
#pragma unroll
      for (int i = 0; i < 4; ++i)
        vv[i] = *reinterpret_cast<const float4*>(&vr[sub * 4 + i * 32]);
    }
#pragma unroll
    for (int i = 0; i < 4; ++i) {
      oacc[i].x += p * vv[i].x;
      oacc[i].y += p * vv[i].y;
      oacc[i].z += p * vv[i].z;
      oacc[i].w += p * vv[i].w;
    }
  }

#pragma unroll
  for (int i = 0; i < 4; ++i) {
#pragma unroll
    for (int off = 8; off <= 32; off <<= 1) {
      oacc[i].x += __shfl_xor(oacc[i].x, off, 64);
      oacc[i].y += __shfl_xor(oacc[i].y, off, 64);
      oacc[i].z += __shfl_xor(oacc[i].z, off, 64);
      oacc[i].w += __shfl_xor(oacc[i].w, off, 64);
    }
  }
  if (grp == 0) {
#pragma unroll
    for (int i = 0; i < 4; ++i)
      *reinterpret_cast<float4*>(&ow[wave][sub * 4 + i * 32]) = oacc[i];
  }
  __syncthreads();
  if (tid < HD) {
    const float o = ow[0][tid] + ow[1][tid] + ow[2][tid] + ow[3][tid];
    o_part[((size_t)bh * NCHUNK + c) * HD + tid] = o;
    if (tid == 0) {
      m_part[bh * NCHUNK + c] = m;
      l_part[bh * NCHUNK + c] = l;
    }
  }
}

__global__ __launch_bounds__(128) void attn_combine(
    const float* __restrict__ o_part, const float* __restrict__ m_part,
    const float* __restrict__ l_part, const int* __restrict__ ctx_len,
    float* __restrict__ attn_out) {
  const int bh = blockIdx.x;
  const int b = bh >> 5, h = bh & 31;
  const int ctx = ctx_len[b];
  const int nc = (ctx + TPC - 1) / TPC;
  const int d = threadIdx.x;

  float M = -1e30f;
  for (int c = 0; c < nc; ++c) M = fmaxf(M, m_part[bh * NCHUNK + c]);
  float L = 0.f, o = 0.f;
  for (int c = 0; c < nc; ++c) {
    const float sc = expf(m_part[bh * NCHUNK + c] - M);
    L += l_part[bh * NCHUNK + c] * sc;
    o += o_part[((size_t)bh * NCHUNK + c) * HD + d] * sc;
  }
  attn_out[(size_t)b * HID + h * HD + d] = o / L;
}

extern "C" void kernel_launch(void* const* d_in, const int* in_sizes, int n_in,
                              void* d_out, int out_size, void* d_ws, size_t ws_size,
                              hipStream_t stream) {
  const float* hidden = (const float*)d_in[0];   // (16,1,4096)
  const float* qkv_w  = (const float*)d_in[1];   // (12288,4096)
  const float* out_w  = (const float*)d_in[2];   // (4096,4096)
  const float* cs     = (const float*)d_in[3];   // (2048,128)
  const float* kc     = (const float*)d_in[4];   // (1024,16,32,128)
  const float* vc     = (const float*)d_in[5];   // (1024,16,32,128)
  const int* pos      = (const int*)d_in[6];     // (16,1)
  const int* bt       = (const int*)d_in[7];     // (16,64)
  // d_in[8] = slots (unused: substitution at s == ctx-1)
  const int* cl       = (const int*)d_in[9];     // (16,)
  float* out = (float*)d_out;                    // (16,1,4096)

  float* ws_qkv_p = (float*)d_ws;                              // KSPLIT*16*12288
  float* ws_attn  = ws_qkv_p + (size_t)KSPLIT * 16 * QKV_R;    // 16*4096
  float* ws_out_p = ws_attn + NBATCH * HID;                    // KSPLIT*16*4096
  float* ws_op    = ws_out_p + (size_t)KSPLIT * 16 * HID;      // 512*8*128
  float* ws_m     = ws_op + (size_t)NBATCH * NH * NCHUNK * HD; // 512*8
  float* ws_l     = ws_m + NBATCH * NH * NCHUNK;               // 512*8

  gemv16_v6<<<dim3(QKV_R / 4, KSPLIT), 256, 0, stream>>>(hidden, qkv_w,
                                                         ws_qkv_p, QKV_R);
  attn_split<<<dim3(NBATCH * NH, NCHUNK), 256, 0, stream>>>(
      ws_qkv_p, cs, kc, vc, pos, bt, cl, ws_op, ws_m, ws_l);
  attn_combine<<<NBATCH * NH, 128, 0, stream>>>(ws_op, ws_m, ws_l, cl, ws_attn);
  gemv16_v6<<<dim3(HID / 4, KSPLIT), 256, 0, stream>>>(ws_attn, out_w,
                                                       ws_out_p, HID);
  combine_k<<<(16 * HID + 255) / 256, 256, 0, stream>>>(ws_out_p, out, HID);
}

// Round 9
// 222.562 us; speedup vs baseline: 3.7787x; 1.5889x over previous
//
#include <hip/hip_runtime.h>
#include <math.h>

#define NH 32
#define HD 128
#define BS 16
#define MAXB 64
#define HID 4096
#define NBATCH 16
#define QKV_R 12288
#define SCALE 0.08838834764831845f  // 1/sqrt(128)
#define TPC 128                     // tokens per chunk (attn split)
#define NCHUNK 8                    // max chunks (MAXB*BS / TPC)
#define KSPLIT 8
#define KC 512                      // 4096 / KSPLIT

// v7 burst gemv: grid (R/4, KSPLIT). Block = 4 waves; wave w owns batches
// 4w..4w+3 and K-slice [kc0, kc0+512). Each lane burst-loads its whole W
// slice (8 float4) and x slice (8 float4) -- 16 independent loads in flight,
// one latency, then pure VALU. No per-iter convoy. ~92 VGPRs, no clamp.
__global__ __launch_bounds__(256) void gemv16_v7(
    const float* __restrict__ x, const float* __restrict__ W,
    float* __restrict__ yp, int R) {
  const int r0 = blockIdx.x * 4;
  const int kc0 = blockIdx.y * KC;
  const int tid = threadIdx.x;
  const int wave = tid >> 6, lane = tid & 63;
  const int b0 = wave * 4;

  const float* wb = W + (size_t)r0 * 4096 + kc0 + lane * 4;
  float4 wv[4][2];
#pragma unroll
  for (int r = 0; r < 4; ++r)
#pragma unroll
    for (int it = 0; it < 2; ++it)
      wv[r][it] = *reinterpret_cast<const float4*>(
          wb + (size_t)r * 4096 + it * 256);

  float4 xv[4][2];
#pragma unroll
  for (int bb = 0; bb < 4; ++bb)
#pragma unroll
    for (int it = 0; it < 2; ++it)
      xv[bb][it] = *reinterpret_cast<const float4*>(
          &x[(size_t)(b0 + bb) * 4096 + kc0 + it * 256 + lane * 4]);

  float acc[4][4];
#pragma unroll
  for (int r = 0; r < 4; ++r)
#pragma unroll
    for (int bb = 0; bb < 4; ++bb) acc[r][bb] = 0.f;

#pragma unroll
  for (int it = 0; it < 2; ++it)
#pragma unroll
    for (int r = 0; r < 4; ++r)
#pragma unroll
      for (int bb = 0; bb < 4; ++bb)
        acc[r][bb] += wv[r][it].x * xv[bb][it].x + wv[r][it].y * xv[bb][it].y +
                      wv[r][it].z * xv[bb][it].z + wv[r][it].w * xv[bb][it].w;

#pragma unroll
  for (int r = 0; r < 4; ++r)
#pragma unroll
    for (int bb = 0; bb < 4; ++bb) {
      float v = acc[r][bb];
#pragma unroll
      for (int off = 32; off; off >>= 1) v += __shfl_xor(v, off, 64);
      if (lane == 0)
        yp[((size_t)blockIdx.y * 16 + b0 + bb) * R + r0 + r] = v;
    }
}

// Sum KSPLIT partial slices into y (used for the output projection).
__global__ __launch_bounds__(256) void combine_k(
    const float* __restrict__ p, float* __restrict__ y, int R) {
  const int i = blockIdx.x * 256 + threadIdx.x;
  if (i < 16 * R) {
    float v = 0.f;
#pragma unroll
    for (int c = 0; c < KSPLIT; ++c) v += p[(size_t)c * 16 * R + i];
    y[i] = v;
  }
}

// Flash-decoding chunk kernel. Reads qkv as KSPLIT partial slices and sums
// them while building q/k/v (folded combine). New k/v substituted at
// s == ctx-1 (block_tables is a permutation => disjoint rows).
__global__ __launch_bounds__(256) void attn_split(
    const float* __restrict__ qkv_p, const float* __restrict__ cs_cache,
    const float* __restrict__ kcache, const float* __restrict__ vcache,
    const int* __restrict__ pos_ids, const int* __restrict__ btab,
    const int* __restrict__ ctx_len, float* __restrict__ o_part,
    float* __restrict__ m_part, float* __restrict__ l_part) {
  const int bh = blockIdx.x;
  const int b = bh >> 5, h = bh & 31;
  const int c = blockIdx.y;
  const int ctx = ctx_len[b];
  const int t0 = c * TPC;
  if (t0 >= ctx) return;
  const int tend = min(t0 + TPC, ctx);
  const int n = tend - t0;
  const int last = ctx - 1;

  const int tid = threadIdx.x;
  const int wave = tid >> 6, lane = tid & 63;
  const int grp = lane >> 3, sub = lane & 7;
  const int gid = wave * 8 + grp;

  __shared__ float q_rot[HD], k_rot[HD], v_new[HD];
  __shared__ float scores[TPC];
  __shared__ int blk_base[TPC / BS];
  __shared__ float redm[4], reds[4];
  __shared__ float ow[4][HD];

  const int pos = pos_ids[b];
  const size_t CS = (size_t)16 * QKV_R;  // slice stride in partial buffer
  const float* qp = qkv_p + (size_t)b * QKV_R + h * HD;
  const float* cs = cs_cache + (size_t)pos * HD;

  if (tid < 64) {
    const float co = cs[tid], si = cs[64 + tid];
    float a1 = 0.f, a2 = 0.f, b1 = 0.f, b2 = 0.f;
    const float* kp = qp + 4096;
#pragma unroll
    for (int s = 0; s < KSPLIT; ++s) {
      a1 += qp[s * CS + tid];
      a2 += qp[s * CS + tid + 64];
      b1 += kp[s * CS + tid];
      b2 += kp[s * CS + tid + 64];
    }
    q_rot[tid] = a1 * co - a2 * si;
    q_rot[tid + 64] = a2 * co + a1 * si;
    k_rot[tid] = b1 * co - b2 * si;
    k_rot[tid + 64] = b2 * co + b1 * si;
  } else if (tid < 192) {
    const int d = tid - 64;
    const float* vp = qp + 8192;
    float v = 0.f;
#pragma unroll
    for (int s = 0; s < KSPLIT; ++s) v += vp[s * CS + d];
    v_new[d] = v;
  } else if (tid < 192 + TPC / BS) {
    const int i = tid - 192;
    const int bt_idx = (t0 >> 4) + i;
    blk_base[i] = (bt_idx < MAXB) ? btab[b * MAXB + bt_idx] : 0;
  }
  __syncthreads();

  float4 qf[4];
#pragma unroll
  for (int i = 0; i < 4; ++i)
    qf[i] = *reinterpret_cast<const float4*>(&q_rot[sub * 4 + i * 32]);

  for (int t = t0 + gid; t < tend; t += 32) {
    float4 kv[4];
    if (t == last) {
#pragma unroll
      for (int i = 0; i < 4; ++i)
        kv[i] = *reinterpret_cast<const float4*>(&k_rot[sub * 4 + i * 32]);
    } else {
      const int blk = blk_base[(t - t0) >> 4];
      const float* kr = kcache + ((((size_t)blk << 4) + (t & 15)) * NH + h) * HD;
#pragma unroll
      for (int i = 0; i < 4; ++i)
        kv[i] = *reinterpret_cast<const float4*>(&kr[sub * 4 + i * 32]);
    }
    float d0 = kv[0].x * qf[0].x + kv[0].y * qf[0].y + kv[0].z * qf[0].z + kv[0].w * qf[0].w;
    float d1 = kv[1].x * qf[1].x + kv[1].y * qf[1].y + kv[1].z * qf[1].z + kv[1].w * qf[1].w;
    float d2 = kv[2].x * qf[2].x + kv[2].y * qf[2].y + kv[2].z * qf[2].z + kv[2].w * qf[2].w;
    float d3 = kv[3].x * qf[3].x + kv[3].y * qf[3].y + kv[3].z * qf[3].z + kv[3].w * qf[3].w;
    float d = (d0 + d1) + (d2 + d3);
    d += __shfl_xor(d, 1, 64);
    d += __shfl_xor(d, 2, 64);
    d += __shfl_xor(d, 4, 64);
    if (sub == 0) scores[t - t0] = d * SCALE;
  }
  __syncthreads();

  float m = (tid < n) ? scores[tid] : -1e30f;
#pragma unroll
  for (int off = 32; off; off >>= 1) m = fmaxf(m, __shfl_xor(m, off, 64));
  if (lane == 0) redm[wave] = m;
  __syncthreads();
  m = fmaxf(fmaxf(redm[0], redm[1]), fmaxf(redm[2], redm[3]));

  float ssum = 0.f;
  if (tid < n) {
    const float e = expf(scores[tid] - m);
    scores[tid] = e;
    ssum = e;
  }
#pragma unroll
  for (int off = 32; off; off >>= 1) ssum += __shfl_xor(ssum, off, 64);
  if (lane == 0) reds[wave] = ssum;
  __syncthreads();
  const float l = reds[0] + reds[1] + reds[2] + reds[3];

  float4 oacc[4];
#pragma unroll
  for (int i = 0; i < 4; ++i) oacc[i] = make_float4(0.f, 0.f, 0.f, 0.f);

  for (int t = t0 + gid; t < tend; t += 32) {
    const float p = scores[t - t0];
    float4 vv[4];
    if (t == last) {
#pragma unroll
      for (int i = 0; i < 4; ++i)
        vv[i] = *reinterpret_cast<const float4*>(&v_new[sub * 4 + i * 32]);
    } else {
      const int blk = blk_base[(t - t0) >> 4];
      const float* vr = vcache + ((((size_t)blk << 4) + (t & 15)) * NH + h) * HD;
#pragma unroll
      for (int i = 0; i < 4; ++i)
        vv[i] = *reinterpret_cast<const float4*>(&vr[sub * 4 + i * 32]);
    }
#pragma unroll
    for (int i = 0; i < 4; ++i) {
      oacc[i].x += p * vv[i].x;
      oacc[i].y += p * vv[i].y;
      oacc[i].z += p * vv[i].z;
      oacc[i].w += p * vv[i].w;
    }
  }

#pragma unroll
  for (int i = 0; i < 4; ++i) {
#pragma unroll
    for (int off = 8; off <= 32; off <<= 1) {
      oacc[i].x += __shfl_xor(oacc[i].x, off, 64);
      oacc[i].y += __shfl_xor(oacc[i].y, off, 64);
      oacc[i].z += __shfl_xor(oacc[i].z, off, 64);
      oacc[i].w += __shfl_xor(oacc[i].w, off, 64);
    }
  }
  if (grp == 0) {
#pragma unroll
    for (int i = 0; i < 4; ++i)
      *reinterpret_cast<float4*>(&ow[wave][sub * 4 + i * 32]) = oacc[i];
  }
  __syncthreads();
  if (tid < HD) {
    const float o = ow[0][tid] + ow[1][tid] + ow[2][tid] + ow[3][tid];
    o_part[((size_t)bh * NCHUNK + c) * HD + tid] = o;
    if (tid == 0) {
      m_part[bh * NCHUNK + c] = m;
      l_part[bh * NCHUNK + c] = l;
    }
  }
}

__global__ __launch_bounds__(128) void attn_combine(
    const float* __restrict__ o_part, const float* __restrict__ m_part,
    const float* __restrict__ l_part, const int* __restrict__ ctx_len,
    float* __restrict__ attn_out) {
  const int bh = blockIdx.x;
  const int b = bh >> 5, h = bh & 31;
  const int ctx = ctx_len[b];
  const int nc = (ctx + TPC - 1) / TPC;
  const int d = threadIdx.x;

  float M = -1e30f;
  for (int c = 0; c < nc; ++c) M = fmaxf(M, m_part[bh * NCHUNK + c]);
  float L = 0.f, o = 0.f;
  for (int c = 0; c < nc; ++c) {
    const float sc = expf(m_part[bh * NCHUNK + c] - M);
    L += l_part[bh * NCHUNK + c] * sc;
    o += o_part[((size_t)bh * NCHUNK + c) * HD + d] * sc;
  }
  attn_out[(size_t)b * HID + h * HD + d] = o / L;
}

extern "C" void kernel_launch(void* const* d_in, const int* in_sizes, int n_in,
                              void* d_out, int out_size, void* d_ws, size_t ws_size,
                              hipStream_t stream) {
  const float* hidden = (const float*)d_in[0];   // (16,1,4096)
  const float* qkv_w  = (const float*)d_in[1];   // (12288,4096)
  const float* out_w  = (const float*)d_in[2];   // (4096,4096)
  const float* cs     = (const float*)d_in[3];   // (2048,128)
  const float* kc     = (const float*)d_in[4];   // (1024,16,32,128)
  const float* vc     = (const float*)d_in[5];   // (1024,16,32,128)
  const int* pos      = (const int*)d_in[6];     // (16,1)
  const int* bt       = (const int*)d_in[7];     // (16,64)
  // d_in[8] = slots (unused: substitution at s == ctx-1)
  const int* cl       = (const int*)d_in[9];     // (16,)
  float* out = (float*)d_out;                    // (16,1,4096)

  float* ws_qkv_p = (float*)d_ws;                              // KSPLIT*16*12288
  float* ws_attn  = ws_qkv_p + (size_t)KSPLIT * 16 * QKV_R;    // 16*4096
  float* ws_out_p = ws_attn + NBATCH * HID;                    // KSPLIT*16*4096
  float* ws_op    = ws_out_p + (size_t)KSPLIT * 16 * HID;      // 512*8*128
  float* ws_m     = ws_op + (size_t)NBATCH * NH * NCHUNK * HD; // 512*8
  float* ws_l     = ws_m + NBATCH * NH * NCHUNK;               // 512*8

  gemv16_v7<<<dim3(QKV_R / 4, KSPLIT), 256, 0, stream>>>(hidden, qkv_w,
                                                         ws_qkv_p, QKV_R);
  attn_split<<<dim3(NBATCH * NH, NCHUNK), 256, 0, stream>>>(
      ws_qkv_p, cs, kc, vc, pos, bt, cl, ws_op, ws_m, ws_l);
  attn_combine<<<NBATCH * NH, 128, 0, stream>>>(ws_op, ws_m, ws_l, cl, ws_attn);
  gemv16_v7<<<dim3(HID / 4, KSPLIT), 256, 0, stream>>>(ws_attn, out_w,
                                                       ws_out_p, HID);
  combine_k<<<(16 * HID + 255) / 256, 256, 0, stream>>>(ws_out_p, out, HID);
}